// Round 7
// baseline (461.372 us; speedup 1.0000x reference)
//
#include <hip/hip_runtime.h>
#include <math.h>

#define N_NODES 50000
#define N_EDGES 800000
#define D_IN    128
#define ED_IN   64
#define HU      128   // H*U
#define NH      4
#define UD      32

typedef float fx4 __attribute__((ext_vector_type(4)));
typedef short s16x8 __attribute__((ext_vector_type(8)));
typedef float f32x4 __attribute__((ext_vector_type(4)));

static __device__ __forceinline__ unsigned short f2bf(float f) {
  unsigned u = __float_as_uint(f);
  unsigned r = (u + 0x7FFFu + ((u >> 16) & 1u)) >> 16;
  return (unsigned short)r;
}
static __device__ __forceinline__ float bf_lo(unsigned u) {
  return __uint_as_float(u << 16);
}
static __device__ __forceinline__ float bf_hi(unsigned u) {
  return __uint_as_float(u & 0xFFFF0000u);
}
static __device__ __forceinline__ float bf2f(unsigned short h) {
  return __uint_as_float(((unsigned)h) << 16);
}
// 8-element dot: fp32 a0|a1 against 8 bf16 packed in uint4
static __device__ __forceinline__ float dot8(float4 a0, float4 a1, uint4 kk) {
  return a0.x * bf_lo(kk.x) + a0.y * bf_hi(kk.x)
       + a0.z * bf_lo(kk.y) + a0.w * bf_hi(kk.y)
       + a1.x * bf_lo(kk.z) + a1.y * bf_hi(kk.z)
       + a1.z * bf_lo(kk.w) + a1.w * bf_hi(kk.w);
}
static __device__ __forceinline__ float4 f4add(float4 a, float4 b) {
  return make_float4(a.x + b.x, a.y + b.y, a.z + b.z, a.w + b.w);
}

// K0: segment offsets from sorted src. off[n] = lower_bound(src, n); off[N] = E.
__global__ __launch_bounds__(256) void offsets_kernel(
    const int* __restrict__ src, int* __restrict__ off) {
  const int e = blockIdx.x * 256 + threadIdx.x;
  if (e >= N_EDGES) return;
  const int s = src[e];
  const int prev = (e == 0) ? -1 : src[e - 1];
  for (int n = prev + 1; n <= s; ++n) off[n] = e;
  if (e == N_EDGES - 1)
    for (int n = s + 1; n <= N_NODES; ++n) off[n] = N_EDGES;
}

// K0b: pack We (fp32 [64][128]) into bf16 MFMA B-fragments for 16x16x32:
// frag f = nt*2+kh, lane l holds B[k][n] for n = nt*16+(l&15),
// k = kh*32 + (l>>4)*8 + j  (j = 0..7, lane-contiguous 16B record).
__global__ __launch_bounds__(256) void wepack_kernel(
    const float* __restrict__ We, unsigned short* __restrict__ wf) {
  const int fl = blockIdx.x * 256 + threadIdx.x;   // 16 frags * 64 lanes
  if (fl >= 16 * 64) return;
  const int f = fl >> 6, lane = fl & 63;
  const int nt = f >> 1, kh = f & 1;
  const int n = nt * 16 + (lane & 15);
  const int kbase = kh * 32 + (lane >> 4) * 8;
#pragma unroll
  for (int j = 0; j < 8; ++j)
    wf[fl * 8 + j] = f2bf(We[(kbase + j) * HU + n]);
}

// K0c: pack Wq|Wk|Wv (fp32 [128][128] each) into hi/lo bf16 MFMA B-frags.
// frag f = proj*32 + nt*4 + kf; lane l holds W[k][n], n = nt*16+(l&15),
// k = kf*32+(l>>4)*8+j. hi at [fl*8+j], lo at [+96*64*8].
__global__ __launch_bounds__(256) void wqkvpack_kernel(
    const float* __restrict__ Wq, const float* __restrict__ Wk,
    const float* __restrict__ Wv, unsigned short* __restrict__ wqkv) {
  const int fl = blockIdx.x * 256 + threadIdx.x;   // 96 frags * 64 lanes
  if (fl >= 96 * 64) return;
  const int f = fl >> 6, lane = fl & 63;
  const int proj = f >> 5, nt = (f >> 2) & 7, kf = f & 3;
  const float* W = proj == 0 ? Wq : (proj == 1 ? Wk : Wv);
  const int n = nt * 16 + (lane & 15);
  const int kb = kf * 32 + (lane >> 4) * 8;
#pragma unroll
  for (int j = 0; j < 8; ++j) {
    const float v = W[(kb + j) * HU + n];
    const unsigned short h = f2bf(v);
    wqkv[fl * 8 + j] = h;
    wqkv[96 * 64 * 8 + fl * 8 + j] = f2bf(v - bf2f(h));
  }
}

// K1: q/k/v projections via MFMA with 3-term hi/lo split (fp32-grade):
//   acc = xh@Wh + xl@Wh + xh@Wl   (xl@Wl ~ 2^-18, dropped)
// Block = 16 nodes, 4 waves; wave w computes tiles tt = w*6..w*6+5,
// tt -> (proj = tt>>3, nt = tt&7). No LDS. q fp32 (bq+be folded); k,v bf16.
__global__ __launch_bounds__(256) void qkv_kernel(
    const float* __restrict__ x, const s16x8* __restrict__ wqkv,
    const float* __restrict__ bq, const float* __restrict__ be,
    const float* __restrict__ bk, const float* __restrict__ bv,
    float* __restrict__ q, unsigned short* __restrict__ kbf,
    unsigned short* __restrict__ vbf) {
  const int base = blockIdx.x * 16;
  const int t = threadIdx.x;
  const int w = t >> 6, l = t & 63;

  // A fragments: lane l row = base+(l&15), k = kf*32+(l>>4)*8+j
  const float* xr = x + (long)(base + (l & 15)) * D_IN + (l >> 4) * 8;
  s16x8 Ah[4], Al[4];
#pragma unroll
  for (int kf = 0; kf < 4; ++kf) {
    const fx4 c0 = *(const fx4*)(xr + kf * 32);
    const fx4 c1 = *(const fx4*)(xr + kf * 32 + 4);
#pragma unroll
    for (int j = 0; j < 4; ++j) {
      const unsigned short h0 = f2bf(c0[j]);
      const unsigned short h1 = f2bf(c1[j]);
      Ah[kf][j] = (short)h0;     Al[kf][j] = (short)f2bf(c0[j] - bf2f(h0));
      Ah[kf][4 + j] = (short)h1; Al[kf][4 + j] = (short)f2bf(c1[j] - bf2f(h1));
    }
  }

#pragma unroll
  for (int i = 0; i < 6; ++i) {
    const int tt = w * 6 + i;
    const int proj = tt >> 3, nt = tt & 7;
    const int col = nt * 16 + (l & 15);
    f32x4 acc = (f32x4){0.f, 0.f, 0.f, 0.f};
#pragma unroll
    for (int kf = 0; kf < 4; ++kf) {
      const int fr = proj * 32 + nt * 4 + kf;
      const s16x8 Bh = wqkv[fr * 64 + l];
      const s16x8 Bl = wqkv[96 * 64 + fr * 64 + l];
      acc = __builtin_amdgcn_mfma_f32_16x16x32_bf16(Ah[kf], Bh, acc, 0, 0, 0);
      acc = __builtin_amdgcn_mfma_f32_16x16x32_bf16(Al[kf], Bh, acc, 0, 0, 0);
      acc = __builtin_amdgcn_mfma_f32_16x16x32_bf16(Ah[kf], Bl, acc, 0, 0, 0);
    }
    float bias;
    if (proj == 0)      bias = bq[col] + be[col];
    else if (proj == 1) bias = bk[col];
    else                bias = bv[col];
#pragma unroll
    for (int r = 0; r < 4; ++r) {
      const long node = base + (l >> 4) * 4 + r;
      const float val = acc[r] + bias;
      if (proj == 0)      q[node * HU + col] = val;
      else if (proj == 1) kbf[node * HU + col] = f2bf(val);
      else                vbf[node * HU + col] = f2bf(val);
    }
  }
}

// K2: 64 edges per 256-thread block, TWO-PHASE over head-pairs.
//   Both phases' k quarters hoisted to the top (cold L2/L3 gather issued
//   with the ef loads); fences use sched_barrier(0x30) so VMEM reads
//   (phase-1 q / wf B-frags) may cross while DS/VALU/MFMA stay pinned.
__global__ __launch_bounds__(256) void score_kernel(
    const float* __restrict__ ef,
    const int* __restrict__ src, const int* __restrict__ dst,
    const float* __restrict__ q, const unsigned short* __restrict__ kbf,
    const s16x8* __restrict__ wf,
    float* __restrict__ scores) {
  __shared__ __align__(16) float ehs[4][16 * 64];   // 16 KB: 4 KB per wave
  const int t = threadIdx.x;
  const int w = t >> 6, l = t & 63;
  const long ebase = (long)blockIdx.x * 64;
  const int e = (int)(ebase + w * 16 + (l >> 2));
  const int hl = (l >> 1) & 1, half = l & 1;
  const int s = src[e], d = dst[e];

  // hoist BOTH phases' k quarters: lane covers bf16 cols [h*32+half*16, +16)
  // for h = hl (ph0) and h = 2+hl (ph1); 4x 16B, one 256B row per edge-quad.
  const char* kbp = (const char*)kbf + (long)d * 256 + hl * 64 + half * 32;
  const uint4 k00 = *(const uint4*)(kbp);
  const uint4 k01 = *(const uint4*)(kbp + 16);
  const uint4 k10 = *(const uint4*)(kbp + 128);
  const uint4 k11 = *(const uint4*)(kbp + 144);

  // A operand (shared by both phases): lane l holds ef[arow][k],
  // k = kh*32 + (l>>4)*8 + j
  const int arow = (int)(ebase + w * 16 + (l & 15));
  const fx4* ap = (const fx4*)(ef + (long)arow * ED_IN + (l >> 4) * 8);
  const fx4 a00 = __builtin_nontemporal_load(ap);
  const fx4 a01 = __builtin_nontemporal_load(ap + 1);
  const fx4 a10 = __builtin_nontemporal_load(ap + 8);
  const fx4 a11 = __builtin_nontemporal_load(ap + 9);
  s16x8 A0, A1;
  A0[0] = (short)f2bf(a00[0]); A0[1] = (short)f2bf(a00[1]);
  A0[2] = (short)f2bf(a00[2]); A0[3] = (short)f2bf(a00[3]);
  A0[4] = (short)f2bf(a01[0]); A0[5] = (short)f2bf(a01[1]);
  A0[6] = (short)f2bf(a01[2]); A0[7] = (short)f2bf(a01[3]);
  A1[0] = (short)f2bf(a10[0]); A1[1] = (short)f2bf(a10[1]);
  A1[2] = (short)f2bf(a10[2]); A1[3] = (short)f2bf(a10[3]);
  A1[4] = (short)f2bf(a11[0]); A1[5] = (short)f2bf(a11[1]);
  A1[6] = (short)f2bf(a11[2]); A1[7] = (short)f2bf(a11[3]);

  float* __restrict__ ehw = ehs[w];
  const int nb = l & 15, gbase = (l >> 4) * 4;
  const int rloc = l >> 2;                 // score-phase local edge row
  const int swzr = (rloc & 7) << 4;

#pragma unroll
  for (int ph = 0; ph < 2; ++ph) {
    // 8 MFMAs: quarter-tiles nt = ph*4 .. ph*4+3, K=64 over two kh frags
    f32x4 acc[4];
#pragma unroll
    for (int ntl = 0; ntl < 4; ++ntl) acc[ntl] = (f32x4){0.f, 0.f, 0.f, 0.f};
#pragma unroll
    for (int ntl = 0; ntl < 4; ++ntl) {
      const int f = (ph * 4 + ntl) * 2;
      const s16x8 B0 = wf[(f + 0) * 64 + l];
      const s16x8 B1 = wf[(f + 1) * 64 + l];
      acc[ntl] = __builtin_amdgcn_mfma_f32_16x16x32_bf16(A0, B0, acc[ntl], 0, 0, 0);
      acc[ntl] = __builtin_amdgcn_mfma_f32_16x16x32_bf16(A1, B1, acc[ntl], 0, 0, 0);
    }

    // half-tile scatter: local row m = gbase+r, local col n = ntl*16+nb,
    // byte-in-row ^= (m&7)<<4 (same swizzle on read side below)
#pragma unroll
    for (int ntl = 0; ntl < 4; ++ntl) {
#pragma unroll
      for (int r = 0; r < 4; ++r) {
        const int m = gbase + r;
        const int b = (ntl * 16 + nb) * 4;
        ehw[(m * 256 + (b ^ ((m & 7) << 4))) >> 2] = acc[ntl][r];
      }
    }
    // wave-local fence: this wave's writes cover exactly the rows it reads.
    // sched_barrier(0x30): VMEM reads may cross (phase-1 q/wf prefetch);
    // DS, VALU, MFMA pinned -> rule-#18 hazard still fenced.
    asm volatile("s_waitcnt lgkmcnt(0)" ::: "memory");
    __builtin_amdgcn_sched_barrier(0x30);

    // score partial: lane handles (edge rloc, head h=ph*2+hl), cols half*16..+15
    const int h = ph * 2 + hl;
    const char* ehp = (const char*)(ehw + rloc * 64);
    const int cb = (l & 3) * 64;   // = hl*128 + half*64 bytes within half-row
    const float4 e0 = *(const float4*)(ehp + ((cb + 0)  ^ swzr));
    const float4 e1 = *(const float4*)(ehp + ((cb + 16) ^ swzr));
    const float4 e2 = *(const float4*)(ehp + ((cb + 32) ^ swzr));
    const float4 e3 = *(const float4*)(ehp + ((cb + 48) ^ swzr));

    const float4* qp = (const float4*)(q + (long)s * HU + h * 32 + half * 16);
    const float4 q0 = qp[0], q1 = qp[1], q2 = qp[2], q3 = qp[3];
    const uint4 k0 = ph ? k10 : k00;
    const uint4 k1 = ph ? k11 : k01;

    float p = dot8(f4add(q0, e0), f4add(q1, e1), k0)
            + dot8(f4add(q2, e2), f4add(q3, e3), k1);
    p += __shfl_xor(p, 1, 64);             // combine the two 16-col halves
    if (!half)
      __builtin_nontemporal_store(p, scores + (long)e * NH + h);

    // ensure phase-A reads retired before phase-B overwrites the half-tile
    asm volatile("s_waitcnt lgkmcnt(0)" ::: "memory");
    __builtin_amdgcn_sched_barrier(0x30);
  }
}

// K3: one WAVE per node (4 nodes per 256-thread block).
// Lane l: features 2l,2l+1 (head h=l>>4); softmax in 16-lane shuffle groups.
// dst index per edge is wave-uniform -> readlane (SALU) instead of shfl (DS);
// Wo staged block-wide in LDS (one barrier at start).
__global__ __launch_bounds__(256) void aggregate_kernel(
    const int* __restrict__ off, const int* __restrict__ dst,
    const float* __restrict__ scores, const unsigned* __restrict__ v2,
    const float* __restrict__ Wo, const float* __restrict__ bo,
    float* __restrict__ out) {
  const int wv = threadIdx.x >> 6, l = threadIdx.x & 63;
  const int n = blockIdx.x * 4 + wv;
  const int h = l >> 4, q16 = l & 15;
  __shared__ float att[4][HU];
  __shared__ __align__(16) float wos[HU * UD];   // 16 KB

  // stage Wo once per block (coalesced float4), shared by all 4 waves
  {
    const fx4* wop = (const fx4*)Wo;
    fx4* wosp = (fx4*)wos;
#pragma unroll
    for (int r = 0; r < 4; ++r)
      wosp[threadIdx.x + 256 * r] = wop[threadIdx.x + 256 * r];
  }
  __syncthreads();

  const int start = off[n], end = off[n + 1];
  float m = -INFINITY, lsum = 0.f, a0 = 0.f, a1 = 0.f;
  for (int cs = start; cs < end; cs += 16) {
    const int e = cs + q16;
    const bool live = (e < end);
    const float sc = live ? __builtin_nontemporal_load(scores + (long)e * NH + h)
                          : -INFINITY;
    const int dl = live ? dst[e] : 0;
    float mc = sc;
#pragma unroll
    for (int o = 8; o > 0; o >>= 1) mc = fmaxf(mc, __shfl_xor(mc, o, 16));
    const float nm = fmaxf(m, mc);          // finite: >=1 live edge per chunk
    const float corr = __expf(m - nm);      // 0 on first chunk
    const float w = __expf(sc - nm);        // 0 for dead lanes
    float ws = w;
#pragma unroll
    for (int o = 8; o > 0; o >>= 1) ws += __shfl_xor(ws, o, 16);
    lsum = lsum * corr + ws;
    a0 *= corr; a1 *= corr; m = nm;
    // dead entries have w=0, dj=0 (harmless cached row-0 load).
    // dj is wave-uniform (one wave = one node): readlane -> SGPR base,
    // frees the DS pipe; only the per-head weight needs a shuffle.
#pragma unroll
    for (int j = 0; j < 16; ++j) {
      const float wj = __shfl(w, (l & 48) + j, 64);
      const int dj = __builtin_amdgcn_readlane(dl, j);
      const unsigned vr = v2[(long)dj * 64 + l];   // 256B coalesced row
      a0 += wj * bf_lo(vr);
      a1 += wj * bf_hi(vr);
    }
  }
  const float inv = (lsum > 0.f) ? 1.f / lsum : 0.f;
  att[wv][2 * l] = a0 * inv;
  att[wv][2 * l + 1] = a1 * inv;
  // wave-synchronous: same wave wrote these LDS entries, no barrier needed
  const int o = l & 31, half = l >> 5;
  float po = 0.f;
#pragma unroll
  for (int f = 0; f < 64; ++f)
    po += att[wv][half * 64 + f] * wos[(half * 64 + f) * UD + o];
  po += __shfl_down(po, 32, 64);
  if (l < 32) out[(long)n * UD + l] = fmaxf(po + bo[l], 0.f);
}

extern "C" void kernel_launch(void* const* d_in, const int* in_sizes, int n_in,
                              void* d_out, int out_size, void* d_ws, size_t ws_size,
                              hipStream_t stream) {
  const float* x  = (const float*)d_in[0];
  const int*   ei = (const int*)d_in[1];
  const float* ef = (const float*)d_in[2];
  const float* Wq = (const float*)d_in[3];
  const float* bq = (const float*)d_in[4];
  const float* Wk = (const float*)d_in[5];
  const float* bk = (const float*)d_in[6];
  const float* Wv = (const float*)d_in[7];
  const float* bv = (const float*)d_in[8];
  const float* We = (const float*)d_in[9];
  const float* be = (const float*)d_in[10];
  const float* Wo = (const float*)d_in[11];
  const float* bo = (const float*)d_in[12];
  float* out = (float*)d_out;

  const int* src = ei;             // edge_index[0]
  const int* dst = ei + N_EDGES;   // edge_index[1]

  // ws: q fp32 [N*128] | kbf [N*128] | vbf [N*128] | scores [E*4] | off |
  //     wf (16 frags) | wqkv (96 frags hi + 96 lo)
  float* q = (float*)d_ws;
  unsigned short* kbf = (unsigned short*)(q + (long)N_NODES * HU);
  unsigned short* vbf = kbf + (long)N_NODES * HU;
  float* scores = (float*)(vbf + (long)N_NODES * HU);
  int* off = (int*)(scores + (long)N_EDGES * NH);
  unsigned short* wf = (unsigned short*)(((uintptr_t)(off + N_NODES + 1) + 15)
                                         & ~(uintptr_t)15);
  unsigned short* wqkv = wf + 16 * 64 * 8;   // 16 KB after wf, stays 16B-aligned

  offsets_kernel<<<(N_EDGES + 255) / 256, 256, 0, stream>>>(src, off);
  wepack_kernel<<<4, 256, 0, stream>>>(We, wf);
  wqkvpack_kernel<<<24, 256, 0, stream>>>(Wq, Wk, Wv, wqkv);
  qkv_kernel<<<N_NODES / 16, 256, 0, stream>>>(x, (const s16x8*)wqkv,
                                               bq, be, bk, bv, q, kbf, vbf);
  score_kernel<<<N_EDGES / 64, 256, 0, stream>>>(ef, src, dst, q, kbf,
                                                 (const s16x8*)wf, scores);
  aggregate_kernel<<<N_NODES / 4, 256, 0, stream>>>(off, dst, scores,
                                                    (const unsigned*)vbf, Wo, bo, out);
}